// Round 5
// baseline (204.710 us; speedup 1.0000x reference)
//
#include <hip/hip_runtime.h>

#define BATCH 2
#define NCAM 6
#define CIN 256
#define COUT 80
#define HFEAT 32
#define WFEAT 88
#define HWF (HFEAT * WFEAT)   // 2816
#define NXV 200
#define NYV 200
#define NZV 4
#define NPIX (NXV * NYV)      // 40000
#define BN_EPS 1e-5f
#define CSPLIT 2              // channel halves in k_bev
#define CHALF (COUT / CSPLIT) // 40

// ws layout: featW (B*NCAM*HWF*COUT floats = 10,813,440 B) at offset 0.
#define WS_NEED ((size_t)BATCH * NCAM * HWF * COUT * 4)

// ---------------------------------------------------------------------------
// Combined projection matrix per (b, cam) — folds lidar_aug^-1 and
// (iam_r @ l2i) into one 3x4 matrix + u/v post-offsets.
// ---------------------------------------------------------------------------
__device__ __forceinline__ void compute_cam_mat(int b, int cam,
                                                const float* __restrict__ l2i,
                                                const float* __restrict__ iam,
                                                const float* __restrict__ lam,
                                                float* __restrict__ O /*16*/) {
    const float* L = lam + b * 16;
    const float* A = iam + (b * NCAM + cam) * 16;
    const float* P = l2i + (b * NCAM + cam) * 16;
    float Tl[3][4];
    #pragma unroll
    for (int i = 0; i < 3; i++) {
        #pragma unroll
        for (int j = 0; j < 3; j++) Tl[i][j] = L[j * 4 + i];
        Tl[i][3] = -(L[0 * 4 + i] * L[0 * 4 + 3] +
                     L[1 * 4 + i] * L[1 * 4 + 3] +
                     L[2 * 4 + i] * L[2 * 4 + 3]);
    }
    float Pm[3][4];
    #pragma unroll
    for (int i = 0; i < 3; i++)
        #pragma unroll
        for (int j = 0; j < 4; j++) {
            float s = 0.f;
            #pragma unroll
            for (int k = 0; k < 3; k++) s += A[i * 4 + k] * P[k * 4 + j];
            Pm[i][j] = s;
        }
    #pragma unroll
    for (int i = 0; i < 3; i++) {
        #pragma unroll
        for (int j = 0; j < 4; j++) {
            float s = (j == 3) ? Pm[i][3] : 0.f;
            #pragma unroll
            for (int k = 0; k < 3; k++) s += Pm[i][k] * Tl[k][j];
            O[i * 4 + j] = s;
        }
    }
    O[12] = A[0 * 4 + 3];
    O[13] = A[1 * 4 + 3];
    O[14] = 0.f;
    O[15] = 0.f;
}

// ---------------------------------------------------------------------------
// featW[bc][hw][o] = sum_c W[o][c] * feat[bc][c][hw]
// R4 fix: latency-bound at 15% VALU (1KB in flight/wave). Now 16-deep
// double-buffered register staging: 16 independent coalesced loads (4KB in
// flight per wave) issue while the other 16 feed 320 FMAs (~640cy), fully
// unrolled so all buffer indices are compile-time (no scratch). Block 64,
// grid (44,12,4): same 2112 waves, 8.25 blocks/CU for load balance.
// FMA order (c ascending, j inner) identical to the passing run.
// ---------------------------------------------------------------------------
__global__ __launch_bounds__(64) void k_featw(const float* __restrict__ feat,
                                              const float* __restrict__ W,
                                              float* __restrict__ featW) {
    const int hw = blockIdx.x * 64 + threadIdx.x;    // 0..2815
    const int bc = blockIdx.y;                        // 0..11
    const int og = blockIdx.z;                        // 0..3 (20 outputs each)
    const float* f = feat + (size_t)bc * CIN * HWF + hw;
    const float* w = W + og * 20 * CIN;

    float acc[20];
    #pragma unroll
    for (int j = 0; j < 20; j++) acc[j] = 0.f;

    float fbA[16], fbB[16];
    #pragma unroll
    for (int k = 0; k < 16; k++) fbA[k] = f[(size_t)k * HWF];

    #pragma unroll
    for (int cc = 0; cc < CIN; cc += 32) {
        // issue next 16 loads (c = cc+16 .. cc+31) into B
        #pragma unroll
        for (int k = 0; k < 16; k++) fbB[k] = f[(size_t)(cc + 16 + k) * HWF];
        // consume A (c = cc .. cc+15)
        #pragma unroll
        for (int k = 0; k < 16; k++) {
            float v = fbA[k];
            #pragma unroll
            for (int j = 0; j < 20; j++)
                acc[j] = fmaf(v, w[j * CIN + cc + k], acc[j]);
        }
        // issue next 16 loads (c = cc+32 .. cc+47) into A
        if (cc + 32 < CIN) {
            #pragma unroll
            for (int k = 0; k < 16; k++) fbA[k] = f[(size_t)(cc + 32 + k) * HWF];
        }
        // consume B (c = cc+16 .. cc+31)
        #pragma unroll
        for (int k = 0; k < 16; k++) {
            float v = fbB[k];
            #pragma unroll
            for (int j = 0; j < 20; j++)
                acc[j] = fmaf(v, w[j * CIN + cc + 16 + k], acc[j]);
        }
    }

    float* dst = featW + ((size_t)bc * HWF + hw) * COUT + og * 20;
    #pragma unroll
    for (int j = 0; j < 5; j++) {
        *reinterpret_cast<float4*>(dst + j * 4) =
            make_float4(acc[j * 4], acc[j * 4 + 1], acc[j * 4 + 2], acc[j * 4 + 3]);
    }
}

// ---------------------------------------------------------------------------
// Projection of one voxel point -> (cam*HWF + v*WFEAT + u) or -1.
// rintf == jnp.round (half-even); strict Z>0; bounds in float space before
// the int cast; LAST valid camera wins (iterate 5..0).
// ---------------------------------------------------------------------------
__device__ __forceinline__ int project_point(const float* __restrict__ M /*6*16*/,
                                             float x, float y, float z) {
    for (int cam = NCAM - 1; cam >= 0; --cam) {
        const float* m = M + cam * 16;
        float Z = m[8] * x + m[9] * y + m[10] * z + m[11];
        if (Z > 0.f) {
            float u = (m[0] * x + m[1] * y + m[2] * z + m[3]) / Z + m[12];
            float v = (m[4] * x + m[5] * y + m[6] * z + m[7]) / Z + m[13];
            float uf = rintf(u * 0.125f);   // stride = 8, exact pow2 scale
            float vf = rintf(v * 0.125f);
            if (uf >= 0.f && uf < (float)WFEAT && vf >= 0.f && vf < (float)HFEAT) {
                return cam * HWF + (int)vf * WFEAT + (int)uf;
            }
        }
    }
    return -1;
}

// ---------------------------------------------------------------------------
// BN scale / folded-bias precompute into LDS (per block).
// ---------------------------------------------------------------------------
__device__ __forceinline__ void bn_precompute(const float* __restrict__ cb,
                                              const float* __restrict__ gamma,
                                              const float* __restrict__ beta,
                                              const float* __restrict__ mean,
                                              const float* __restrict__ var,
                                              float* __restrict__ s_scale,
                                              float* __restrict__ s_bias) {
    for (int o = threadIdx.x; o < COUT; o += 64) {
        float sc = gamma[o] / sqrtf(var[o] + BN_EPS);
        s_scale[o] = sc;
        s_bias[o] = (cb[o] - mean[o]) * sc + beta[o];
    }
}

// ---------------------------------------------------------------------------
// Main BEV kernel (unchanged from R3; awaiting its counters): 1 wave/block,
// lane = BEV pixel, block handles 40 of 80 channels. Branch-free gathers:
// all 4 z offsets precomputed, invalid -> offset 0 (broadcast) killed by
// mask-FMA; 40 independent float4 gathers in flight. grid (625,2,2).
// ---------------------------------------------------------------------------
__global__ __launch_bounds__(64, 2) void k_bev(const float* __restrict__ featW,
                                               const float* __restrict__ l2i,
                                               const float* __restrict__ iam,
                                               const float* __restrict__ lam,
                                               const float* __restrict__ cb,
                                               const float* __restrict__ gamma,
                                               const float* __restrict__ beta,
                                               const float* __restrict__ mean,
                                               const float* __restrict__ var,
                                               float* __restrict__ out) {
    __shared__ float smats[NCAM * 16];
    __shared__ float s_scale[COUT];
    __shared__ float s_bias[COUT];
    const int b = blockIdx.y;
    const int cs = blockIdx.z;          // channel half: 0 or 1
    if (threadIdx.x < NCAM)
        compute_cam_mat(b, threadIdx.x, l2i, iam, lam, smats + threadIdx.x * 16);
    bn_precompute(cb, gamma, beta, mean, var, s_scale, s_bias);
    __syncthreads();

    const int P = blockIdx.x * 64 + threadIdx.x;
    const int ix = P / NYV, iy = P % NYV;
    const float x = ix * 0.5f - 50.0f;
    const float y = iy * 0.5f - 50.0f;

    const float* base = featW + (size_t)b * NCAM * HWF * COUT + cs * CHALF;
    const float4* src[NZV];
    float vmask[NZV];
    #pragma unroll
    for (int iz = 0; iz < NZV; ++iz) {
        float z = iz * 1.5f - 4.7f;
        int off = project_point(smats, x, y, z);
        vmask[iz] = (off >= 0) ? 1.0f : 0.0f;
        src[iz] = reinterpret_cast<const float4*>(
            base + (size_t)((off >= 0) ? off : 0) * COUT);
    }

    float4 buf[NZV][10];
    #pragma unroll
    for (int iz = 0; iz < NZV; ++iz)
        #pragma unroll
        for (int i = 0; i < 10; i++) buf[iz][i] = src[iz][i];

    float4 acc[10];
    #pragma unroll
    for (int i = 0; i < 10; i++) acc[i] = make_float4(0.f, 0.f, 0.f, 0.f);
    #pragma unroll
    for (int iz = 0; iz < NZV; ++iz) {
        float m = vmask[iz];
        #pragma unroll
        for (int i = 0; i < 10; i++) {
            acc[i].x = fmaf(m, buf[iz][i].x, acc[i].x);
            acc[i].y = fmaf(m, buf[iz][i].y, acc[i].y);
            acc[i].z = fmaf(m, buf[iz][i].z, acc[i].z);
            acc[i].w = fmaf(m, buf[iz][i].w, acc[i].w);
        }
    }

    float* op = out + ((size_t)b * COUT + cs * CHALF) * NPIX + P;
    #pragma unroll
    for (int i = 0; i < 10; i++) {
        float a[4] = {acc[i].x, acc[i].y, acc[i].z, acc[i].w};
        #pragma unroll
        for (int j = 0; j < 4; j++) {
            int o = cs * CHALF + i * 4 + j;
            float val = fmaf(a[j], s_scale[o], s_bias[o]);
            op[(size_t)(i * 4 + j) * NPIX] = fmaxf(val, 0.f);
        }
    }
}

// ---------------------------------------------------------------------------
// Fallback (only if ws too small): fully fused. Slow but correct.
// ---------------------------------------------------------------------------
__global__ __launch_bounds__(64) void k_bev_fb(const float* __restrict__ feat,
                                               const float* __restrict__ l2i,
                                               const float* __restrict__ iam,
                                               const float* __restrict__ lam,
                                               const float* __restrict__ W,
                                               const float* __restrict__ cb,
                                               const float* __restrict__ gamma,
                                               const float* __restrict__ beta,
                                               const float* __restrict__ mean,
                                               const float* __restrict__ var,
                                               float* __restrict__ out) {
    __shared__ float smats[NCAM * 16];
    __shared__ float s_scale[COUT];
    __shared__ float s_bias[COUT];
    const int b = blockIdx.y;
    if (threadIdx.x < NCAM)
        compute_cam_mat(b, threadIdx.x, l2i, iam, lam, smats + threadIdx.x * 16);
    bn_precompute(cb, gamma, beta, mean, var, s_scale, s_bias);
    __syncthreads();

    const int P = blockIdx.x * 64 + threadIdx.x;
    const int ix = P / NYV, iy = P % NYV;
    const float x = ix * 0.5f - 50.0f;
    const float y = iy * 0.5f - 50.0f;

    float acc[COUT];
    #pragma unroll
    for (int o = 0; o < COUT; o++) acc[o] = 0.f;

    for (int iz = 0; iz < NZV; ++iz) {
        float z = iz * 1.5f - 4.7f;
        int off = project_point(smats, x, y, z);
        if (off >= 0) {
            const float* fp = feat + (size_t)b * NCAM * CIN * HWF +
                              (size_t)(off / HWF) * CIN * HWF + (off % HWF);
            for (int c = 0; c < CIN; c++) {
                float fv = fp[(size_t)c * HWF];
                #pragma unroll 8
                for (int o = 0; o < COUT; o++) acc[o] = fmaf(fv, W[o * CIN + c], acc[o]);
            }
        }
    }

    float* op = out + (size_t)b * COUT * NPIX + P;
    for (int o = 0; o < COUT; o++) {
        float val = fmaf(acc[o], s_scale[o], s_bias[o]);
        op[(size_t)o * NPIX] = fmaxf(val, 0.f);
    }
}

extern "C" void kernel_launch(void* const* d_in, const int* in_sizes, int n_in,
                              void* d_out, int out_size, void* d_ws, size_t ws_size,
                              hipStream_t stream) {
    const float* feat  = (const float*)d_in[0];
    const float* l2i   = (const float*)d_in[1];
    const float* iam   = (const float*)d_in[2];
    const float* lam   = (const float*)d_in[3];
    const float* W     = (const float*)d_in[4];
    const float* cb    = (const float*)d_in[5];
    const float* gamma = (const float*)d_in[6];
    const float* beta  = (const float*)d_in[7];
    const float* mean  = (const float*)d_in[8];
    const float* var   = (const float*)d_in[9];
    float* out = (float*)d_out;

    if (ws_size >= WS_NEED) {
        float* featW = (float*)d_ws;
        k_featw<<<dim3(44, 12, 4), 64, 0, stream>>>(feat, W, featW);
        k_bev<<<dim3(625, 2, CSPLIT), 64, 0, stream>>>(featW, l2i, iam, lam, cb,
                                                       gamma, beta, mean, var, out);
    } else {
        k_bev_fb<<<dim3(625, 2), 64, 0, stream>>>(feat, l2i, iam, lam, W, cb, gamma,
                                                  beta, mean, var, out);
    }
}

// Round 8
// 140.846 us; speedup vs baseline: 1.4534x; 1.4534x over previous
//
#include <hip/hip_runtime.h>
#include <hip/hip_fp16.h>

#define BATCH 2
#define NCAM 6
#define CIN 256
#define COUT 80
#define HFEAT 32
#define WFEAT 88
#define HWF (HFEAT * WFEAT)   // 2816
#define NXV 200
#define NYV 200
#define NZV 4
#define NPIX (NXV * NYV)      // 40000
#define BN_EPS 1e-5f
#define CSPLIT 2              // channel halves in k_bev
#define CHALF (COUT / CSPLIT) // 40

// ws layout: featW in fp16 (B*NCAM*HWF*COUT halfs = 5,406,720 B) at offset 0.
#define WS_NEED ((size_t)BATCH * NCAM * HWF * COUT * 2)

// ---------------------------------------------------------------------------
// Combined projection matrix per (b, cam) — folds lidar_aug^-1 and
// (iam_r @ l2i) into one 3x4 matrix + u/v post-offsets.
// ---------------------------------------------------------------------------
__device__ __forceinline__ void compute_cam_mat(int b, int cam,
                                                const float* __restrict__ l2i,
                                                const float* __restrict__ iam,
                                                const float* __restrict__ lam,
                                                float* __restrict__ O /*16*/) {
    const float* L = lam + b * 16;
    const float* A = iam + (b * NCAM + cam) * 16;
    const float* P = l2i + (b * NCAM + cam) * 16;
    float Tl[3][4];
    #pragma unroll
    for (int i = 0; i < 3; i++) {
        #pragma unroll
        for (int j = 0; j < 3; j++) Tl[i][j] = L[j * 4 + i];
        Tl[i][3] = -(L[0 * 4 + i] * L[0 * 4 + 3] +
                     L[1 * 4 + i] * L[1 * 4 + 3] +
                     L[2 * 4 + i] * L[2 * 4 + 3]);
    }
    float Pm[3][4];
    #pragma unroll
    for (int i = 0; i < 3; i++)
        #pragma unroll
        for (int j = 0; j < 4; j++) {
            float s = 0.f;
            #pragma unroll
            for (int k = 0; k < 3; k++) s += A[i * 4 + k] * P[k * 4 + j];
            Pm[i][j] = s;
        }
    #pragma unroll
    for (int i = 0; i < 3; i++) {
        #pragma unroll
        for (int j = 0; j < 4; j++) {
            float s = (j == 3) ? Pm[i][3] : 0.f;
            #pragma unroll
            for (int k = 0; k < 3; k++) s += Pm[i][k] * Tl[k][j];
            O[i * 4 + j] = s;
        }
    }
    O[12] = A[0 * 4 + 3];
    O[13] = A[1 * 4 + 3];
    O[14] = 0.f;
    O[15] = 0.f;
}

// ---------------------------------------------------------------------------
// featW[bc][hw][o] = (half) sum_c W[o][c] * feat[bc][c][hw]
// R5 fix (re-run; R6/R7 were infra failures): R4's stall was the per-c
// scalar W loads (lgkmcnt serialization), not the feat loads. Stage this
// block's 20 W rows into LDS as [c][j] (20KB): inner loop = 5x ds_read_b128
// at a wave-uniform address (broadcast, conflict-free) + 1 coalesced feat
// load + 20 FMAs. FMA order (c ascending, j inner) identical to passing
// runs. grid (44,12,4), block 64.
// ---------------------------------------------------------------------------
__global__ __launch_bounds__(64) void k_featw(const float* __restrict__ feat,
                                              const float* __restrict__ W,
                                              __half* __restrict__ featW) {
    __shared__ __align__(16) float wl[CIN][20];   // [c][j], rows 80B (16B-mult)
    const int l = threadIdx.x;
    const int bc = blockIdx.y;                     // 0..11
    const int og = blockIdx.z;                     // 0..3 (20 outputs each)

    // Stage W^T tile: global coalesced (64 consecutive c), ds_write stride 80B.
    #pragma unroll
    for (int j = 0; j < 20; j++) {
        #pragma unroll
        for (int q = 0; q < 4; q++) {
            int c = q * 64 + l;
            wl[c][j] = W[(og * 20 + j) * CIN + c];
        }
    }
    __syncthreads();

    const int hw = blockIdx.x * 64 + l;            // 0..2815
    const float* f = feat + (size_t)bc * CIN * HWF + hw;

    float acc[20];
    #pragma unroll
    for (int j = 0; j < 20; j++) acc[j] = 0.f;

    #pragma unroll 8
    for (int c = 0; c < CIN; c++) {
        float v = f[(size_t)c * HWF];
        const float4* wr = reinterpret_cast<const float4*>(&wl[c][0]);
        float4 w0 = wr[0], w1 = wr[1], w2 = wr[2], w3 = wr[3], w4 = wr[4];
        acc[0]  = fmaf(v, w0.x, acc[0]);   acc[1]  = fmaf(v, w0.y, acc[1]);
        acc[2]  = fmaf(v, w0.z, acc[2]);   acc[3]  = fmaf(v, w0.w, acc[3]);
        acc[4]  = fmaf(v, w1.x, acc[4]);   acc[5]  = fmaf(v, w1.y, acc[5]);
        acc[6]  = fmaf(v, w1.z, acc[6]);   acc[7]  = fmaf(v, w1.w, acc[7]);
        acc[8]  = fmaf(v, w2.x, acc[8]);   acc[9]  = fmaf(v, w2.y, acc[9]);
        acc[10] = fmaf(v, w2.z, acc[10]);  acc[11] = fmaf(v, w2.w, acc[11]);
        acc[12] = fmaf(v, w3.x, acc[12]);  acc[13] = fmaf(v, w3.y, acc[13]);
        acc[14] = fmaf(v, w3.z, acc[14]);  acc[15] = fmaf(v, w3.w, acc[15]);
        acc[16] = fmaf(v, w4.x, acc[16]);  acc[17] = fmaf(v, w4.y, acc[17]);
        acc[18] = fmaf(v, w4.z, acc[18]);  acc[19] = fmaf(v, w4.w, acc[19]);
    }

    // fp16 store: 10x half2 (4B) stores; dst byte offset is 4B-aligned.
    __half2* dst = reinterpret_cast<__half2*>(
        featW + ((size_t)bc * HWF + hw) * COUT + og * 20);
    #pragma unroll
    for (int j = 0; j < 10; j++)
        dst[j] = __floats2half2_rn(acc[2 * j], acc[2 * j + 1]);
}

// ---------------------------------------------------------------------------
// Projection of one voxel point -> (cam*HWF + v*WFEAT + u) or -1.
// rintf == jnp.round (half-even); strict Z>0; bounds in float space before
// the int cast; LAST valid camera wins (iterate 5..0).
// ---------------------------------------------------------------------------
__device__ __forceinline__ int project_point(const float* __restrict__ M /*6*16*/,
                                             float x, float y, float z) {
    for (int cam = NCAM - 1; cam >= 0; --cam) {
        const float* m = M + cam * 16;
        float Z = m[8] * x + m[9] * y + m[10] * z + m[11];
        if (Z > 0.f) {
            float u = (m[0] * x + m[1] * y + m[2] * z + m[3]) / Z + m[12];
            float v = (m[4] * x + m[5] * y + m[6] * z + m[7]) / Z + m[13];
            float uf = rintf(u * 0.125f);   // stride = 8, exact pow2 scale
            float vf = rintf(v * 0.125f);
            if (uf >= 0.f && uf < (float)WFEAT && vf >= 0.f && vf < (float)HFEAT) {
                return cam * HWF + (int)vf * WFEAT + (int)uf;
            }
        }
    }
    return -1;
}

// ---------------------------------------------------------------------------
// BN scale / folded-bias precompute into LDS (per block).
// ---------------------------------------------------------------------------
__device__ __forceinline__ void bn_precompute(const float* __restrict__ cb,
                                              const float* __restrict__ gamma,
                                              const float* __restrict__ beta,
                                              const float* __restrict__ mean,
                                              const float* __restrict__ var,
                                              float* __restrict__ s_scale,
                                              float* __restrict__ s_bias) {
    for (int o = threadIdx.x; o < COUT; o += 64) {
        float sc = gamma[o] / sqrtf(var[o] + BN_EPS);
        s_scale[o] = sc;
        s_bias[o] = (cb[o] - mean[o]) * sc + beta[o];
    }
}

// ---------------------------------------------------------------------------
// Main BEV kernel: 1 wave/block, lane = BEV pixel, block = 40 of 80 ch.
// Branch-free: 4 z offsets precomputed, invalid -> offset 0 broadcast killed
// by mask-FMA. fp16 featW: 5 uint4 loads per z (80B/lane/z, half of R4's
// traffic and instruction count); convert via __half22float2, fp32 accum.
// grid (625,2,2), block 64.
// ---------------------------------------------------------------------------
__global__ __launch_bounds__(64) void k_bev(const __half* __restrict__ featW,
                                            const float* __restrict__ l2i,
                                            const float* __restrict__ iam,
                                            const float* __restrict__ lam,
                                            const float* __restrict__ cb,
                                            const float* __restrict__ gamma,
                                            const float* __restrict__ beta,
                                            const float* __restrict__ mean,
                                            const float* __restrict__ var,
                                            float* __restrict__ out) {
    __shared__ float smats[NCAM * 16];
    __shared__ float s_scale[COUT];
    __shared__ float s_bias[COUT];
    const int b = blockIdx.y;
    const int cs = blockIdx.z;          // channel half: 0 or 1
    if (threadIdx.x < NCAM)
        compute_cam_mat(b, threadIdx.x, l2i, iam, lam, smats + threadIdx.x * 16);
    bn_precompute(cb, gamma, beta, mean, var, s_scale, s_bias);
    __syncthreads();

    const int P = blockIdx.x * 64 + threadIdx.x;
    const int ix = P / NYV, iy = P % NYV;
    const float x = ix * 0.5f - 50.0f;
    const float y = iy * 0.5f - 50.0f;

    const __half* base = featW + (size_t)b * NCAM * HWF * COUT + cs * CHALF;
    const uint4* src[NZV];
    float vmask[NZV];
    #pragma unroll
    for (int iz = 0; iz < NZV; ++iz) {
        float z = iz * 1.5f - 4.7f;
        int off = project_point(smats, x, y, z);
        vmask[iz] = (off >= 0) ? 1.0f : 0.0f;
        src[iz] = reinterpret_cast<const uint4*>(
            base + (size_t)((off >= 0) ? off : 0) * COUT);
    }

    // Issue all 20 independent 16B gathers (4 z x 5 uint4 = 80B/lane/z).
    uint4 buf[NZV][5];
    #pragma unroll
    for (int iz = 0; iz < NZV; ++iz)
        #pragma unroll
        for (int i = 0; i < 5; i++) buf[iz][i] = src[iz][i];

    float acc[CHALF];
    #pragma unroll
    for (int k = 0; k < CHALF; k++) acc[k] = 0.f;
    #pragma unroll
    for (int iz = 0; iz < NZV; ++iz) {
        float m = vmask[iz];
        #pragma unroll
        for (int i = 0; i < 5; i++) {
            const __half2* h2 = reinterpret_cast<const __half2*>(&buf[iz][i]);
            #pragma unroll
            for (int k = 0; k < 4; k++) {
                float2 fv = __half22float2(h2[k]);
                acc[i * 8 + k * 2]     = fmaf(m, fv.x, acc[i * 8 + k * 2]);
                acc[i * 8 + k * 2 + 1] = fmaf(m, fv.y, acc[i * 8 + k * 2 + 1]);
            }
        }
    }

    float* op = out + ((size_t)b * COUT + cs * CHALF) * NPIX + P;
    #pragma unroll
    for (int k = 0; k < CHALF; k++) {
        int o = cs * CHALF + k;
        float val = fmaf(acc[k], s_scale[o], s_bias[o]);
        op[(size_t)k * NPIX] = fmaxf(val, 0.f);
    }
}

// ---------------------------------------------------------------------------
// Fallback (only if ws too small): fully fused fp32. Slow but correct.
// ---------------------------------------------------------------------------
__global__ __launch_bounds__(64) void k_bev_fb(const float* __restrict__ feat,
                                               const float* __restrict__ l2i,
                                               const float* __restrict__ iam,
                                               const float* __restrict__ lam,
                                               const float* __restrict__ W,
                                               const float* __restrict__ cb,
                                               const float* __restrict__ gamma,
                                               const float* __restrict__ beta,
                                               const float* __restrict__ mean,
                                               const float* __restrict__ var,
                                               float* __restrict__ out) {
    __shared__ float smats[NCAM * 16];
    __shared__ float s_scale[COUT];
    __shared__ float s_bias[COUT];
    const int b = blockIdx.y;
    if (threadIdx.x < NCAM)
        compute_cam_mat(b, threadIdx.x, l2i, iam, lam, smats + threadIdx.x * 16);
    bn_precompute(cb, gamma, beta, mean, var, s_scale, s_bias);
    __syncthreads();

    const int P = blockIdx.x * 64 + threadIdx.x;
    const int ix = P / NYV, iy = P % NYV;
    const float x = ix * 0.5f - 50.0f;
    const float y = iy * 0.5f - 50.0f;

    float acc[COUT];
    #pragma unroll
    for (int o = 0; o < COUT; o++) acc[o] = 0.f;

    for (int iz = 0; iz < NZV; ++iz) {
        float z = iz * 1.5f - 4.7f;
        int off = project_point(smats, x, y, z);
        if (off >= 0) {
            const float* fp = feat + (size_t)b * NCAM * CIN * HWF +
                              (size_t)(off / HWF) * CIN * HWF + (off % HWF);
            for (int c = 0; c < CIN; c++) {
                float fv = fp[(size_t)c * HWF];
                #pragma unroll 8
                for (int o = 0; o < COUT; o++) acc[o] = fmaf(fv, W[o * CIN + c], acc[o]);
            }
        }
    }

    float* op = out + (size_t)b * COUT * NPIX + P;
    for (int o = 0; o < COUT; o++) {
        float val = fmaf(acc[o], s_scale[o], s_bias[o]);
        op[(size_t)o * NPIX] = fmaxf(val, 0.f);
    }
}

extern "C" void kernel_launch(void* const* d_in, const int* in_sizes, int n_in,
                              void* d_out, int out_size, void* d_ws, size_t ws_size,
                              hipStream_t stream) {
    const float* feat  = (const float*)d_in[0];
    const float* l2i   = (const float*)d_in[1];
    const float* iam   = (const float*)d_in[2];
    const float* lam   = (const float*)d_in[3];
    const float* W     = (const float*)d_in[4];
    const float* cb    = (const float*)d_in[5];
    const float* gamma = (const float*)d_in[6];
    const float* beta  = (const float*)d_in[7];
    const float* mean  = (const float*)d_in[8];
    const float* var   = (const float*)d_in[9];
    float* out = (float*)d_out;

    if (ws_size >= WS_NEED) {
        __half* featWp = (__half*)d_ws;
        k_featw<<<dim3(44, 12, 4), 64, 0, stream>>>(feat, W, featWp);
        k_bev<<<dim3(625, 2, CSPLIT), 64, 0, stream>>>(featWp, l2i, iam, lam, cb,
                                                       gamma, beta, mean, var, out);
    } else {
        k_bev_fb<<<dim3(625, 2), 64, 0, stream>>>(feat, l2i, iam, lam, W, cb, gamma,
                                                  beta, mean, var, out);
    }
}

// Round 10
// 134.711 us; speedup vs baseline: 1.5196x; 1.0455x over previous
//
#include <hip/hip_runtime.h>
#include <hip/hip_fp16.h>

#define BATCH 2
#define NCAM 6
#define CIN 256
#define COUT 80
#define HFEAT 32
#define WFEAT 88
#define HWF (HFEAT * WFEAT)   // 2816
#define NXV 200
#define NYV 200
#define NZV 4
#define NPIX (NXV * NYV)      // 40000
#define BN_EPS 1e-5f
#define CSPLIT 2              // channel halves in k_bev
#define CHALF (COUT / CSPLIT) // 40

// ws layout: featW in fp16 (B*NCAM*HWF*COUT halfs = 5,406,720 B) at offset 0.
#define WS_NEED ((size_t)BATCH * NCAM * HWF * COUT * 2)

// ---------------------------------------------------------------------------
// Combined projection matrix per (b, cam) — folds lidar_aug^-1 and
// (iam_r @ l2i) into one 3x4 matrix + u/v post-offsets.
// ---------------------------------------------------------------------------
__device__ __forceinline__ void compute_cam_mat(int b, int cam,
                                                const float* __restrict__ l2i,
                                                const float* __restrict__ iam,
                                                const float* __restrict__ lam,
                                                float* __restrict__ O /*16*/) {
    const float* L = lam + b * 16;
    const float* A = iam + (b * NCAM + cam) * 16;
    const float* P = l2i + (b * NCAM + cam) * 16;
    float Tl[3][4];
    #pragma unroll
    for (int i = 0; i < 3; i++) {
        #pragma unroll
        for (int j = 0; j < 3; j++) Tl[i][j] = L[j * 4 + i];
        Tl[i][3] = -(L[0 * 4 + i] * L[0 * 4 + 3] +
                     L[1 * 4 + i] * L[1 * 4 + 3] +
                     L[2 * 4 + i] * L[2 * 4 + 3]);
    }
    float Pm[3][4];
    #pragma unroll
    for (int i = 0; i < 3; i++)
        #pragma unroll
        for (int j = 0; j < 4; j++) {
            float s = 0.f;
            #pragma unroll
            for (int k = 0; k < 3; k++) s += A[i * 4 + k] * P[k * 4 + j];
            Pm[i][j] = s;
        }
    #pragma unroll
    for (int i = 0; i < 3; i++) {
        #pragma unroll
        for (int j = 0; j < 4; j++) {
            float s = (j == 3) ? Pm[i][3] : 0.f;
            #pragma unroll
            for (int k = 0; k < 3; k++) s += Pm[i][k] * Tl[k][j];
            O[i * 4 + j] = s;
        }
    }
    O[12] = A[0 * 4 + 3];
    O[13] = A[1 * 4 + 3];
    O[14] = 0.f;
    O[15] = 0.f;
}

// ---------------------------------------------------------------------------
// featW[bc][hw][o] = (half) sum_c W[o][c] * feat[bc][c][hw]
// R8 measured: 48us, Occupancy 12.9% (1 wave/SIMD), VALUBusy 20% -> each
// solo wave eats full ds_read->FMA latency per c-iter. R9 fix (re-run;
// acquisition timed out): block 128 (2 waves SHARE one 20KB wl tile) so
// LDS/wave halves -> ~2.5 waves/SIMD resident; second wave covers the
// stall. Inner loop and FMA order unchanged (bitwise-identical output).
// grid (22,12,4), block 128.
// ---------------------------------------------------------------------------
__global__ __launch_bounds__(128) void k_featw(const float* __restrict__ feat,
                                               const float* __restrict__ W,
                                               __half* __restrict__ featW) {
    __shared__ __align__(16) float wl[CIN][20];   // [c][j], rows 80B (16B-mult)
    const int l = threadIdx.x;                     // 0..127
    const int bc = blockIdx.y;                     // 0..11
    const int og = blockIdx.z;                     // 0..3 (20 outputs each)

    // Stage W^T tile: 128 threads x 2 halves per j, global coalesced.
    #pragma unroll
    for (int j = 0; j < 20; j++) {
        wl[l][j]       = W[(og * 20 + j) * CIN + l];
        wl[l + 128][j] = W[(og * 20 + j) * CIN + l + 128];
    }
    __syncthreads();

    const int hw = blockIdx.x * 128 + l;           // 0..2815
    const float* f = feat + (size_t)bc * CIN * HWF + hw;

    float acc[20];
    #pragma unroll
    for (int j = 0; j < 20; j++) acc[j] = 0.f;

    #pragma unroll 8
    for (int c = 0; c < CIN; c++) {
        float v = f[(size_t)c * HWF];
        const float4* wr = reinterpret_cast<const float4*>(&wl[c][0]);
        float4 w0 = wr[0], w1 = wr[1], w2 = wr[2], w3 = wr[3], w4 = wr[4];
        acc[0]  = fmaf(v, w0.x, acc[0]);   acc[1]  = fmaf(v, w0.y, acc[1]);
        acc[2]  = fmaf(v, w0.z, acc[2]);   acc[3]  = fmaf(v, w0.w, acc[3]);
        acc[4]  = fmaf(v, w1.x, acc[4]);   acc[5]  = fmaf(v, w1.y, acc[5]);
        acc[6]  = fmaf(v, w1.z, acc[6]);   acc[7]  = fmaf(v, w1.w, acc[7]);
        acc[8]  = fmaf(v, w2.x, acc[8]);   acc[9]  = fmaf(v, w2.y, acc[9]);
        acc[10] = fmaf(v, w2.z, acc[10]);  acc[11] = fmaf(v, w2.w, acc[11]);
        acc[12] = fmaf(v, w3.x, acc[12]);  acc[13] = fmaf(v, w3.y, acc[13]);
        acc[14] = fmaf(v, w3.z, acc[14]);  acc[15] = fmaf(v, w3.w, acc[15]);
        acc[16] = fmaf(v, w4.x, acc[16]);  acc[17] = fmaf(v, w4.y, acc[17]);
        acc[18] = fmaf(v, w4.z, acc[18]);  acc[19] = fmaf(v, w4.w, acc[19]);
    }

    // fp16 store: 10x half2 (4B) stores; dst byte offset is 4B-aligned.
    __half2* dst = reinterpret_cast<__half2*>(
        featW + ((size_t)bc * HWF + hw) * COUT + og * 20);
    #pragma unroll
    for (int j = 0; j < 10; j++)
        dst[j] = __floats2half2_rn(acc[2 * j], acc[2 * j + 1]);
}

// ---------------------------------------------------------------------------
// Projection of one voxel point -> (cam*HWF + v*WFEAT + u) or -1.
// rintf == jnp.round (half-even); strict Z>0; bounds in float space before
// the int cast; LAST valid camera wins (iterate 5..0).
// ---------------------------------------------------------------------------
__device__ __forceinline__ int project_point(const float* __restrict__ M /*6*16*/,
                                             float x, float y, float z) {
    for (int cam = NCAM - 1; cam >= 0; --cam) {
        const float* m = M + cam * 16;
        float Z = m[8] * x + m[9] * y + m[10] * z + m[11];
        if (Z > 0.f) {
            float u = (m[0] * x + m[1] * y + m[2] * z + m[3]) / Z + m[12];
            float v = (m[4] * x + m[5] * y + m[6] * z + m[7]) / Z + m[13];
            float uf = rintf(u * 0.125f);   // stride = 8, exact pow2 scale
            float vf = rintf(v * 0.125f);
            if (uf >= 0.f && uf < (float)WFEAT && vf >= 0.f && vf < (float)HFEAT) {
                return cam * HWF + (int)vf * WFEAT + (int)uf;
            }
        }
    }
    return -1;
}

// ---------------------------------------------------------------------------
// BN scale / folded-bias precompute into LDS (per block).
// ---------------------------------------------------------------------------
__device__ __forceinline__ void bn_precompute(const float* __restrict__ cb,
                                              const float* __restrict__ gamma,
                                              const float* __restrict__ beta,
                                              const float* __restrict__ mean,
                                              const float* __restrict__ var,
                                              float* __restrict__ s_scale,
                                              float* __restrict__ s_bias) {
    for (int o = threadIdx.x; o < COUT; o += 64) {
        float sc = gamma[o] / sqrtf(var[o] + BN_EPS);
        s_scale[o] = sc;
        s_bias[o] = (cb[o] - mean[o]) * sc + beta[o];
    }
}

// ---------------------------------------------------------------------------
// Main BEV kernel (unchanged; counters pending): 1 wave/block, lane = BEV
// pixel, block = 40 of 80 ch. Branch-free gathers, fp16 featW, fp32 accum.
// grid (625,2,2), block 64.
// ---------------------------------------------------------------------------
__global__ __launch_bounds__(64) void k_bev(const __half* __restrict__ featW,
                                            const float* __restrict__ l2i,
                                            const float* __restrict__ iam,
                                            const float* __restrict__ lam,
                                            const float* __restrict__ cb,
                                            const float* __restrict__ gamma,
                                            const float* __restrict__ beta,
                                            const float* __restrict__ mean,
                                            const float* __restrict__ var,
                                            float* __restrict__ out) {
    __shared__ float smats[NCAM * 16];
    __shared__ float s_scale[COUT];
    __shared__ float s_bias[COUT];
    const int b = blockIdx.y;
    const int cs = blockIdx.z;          // channel half: 0 or 1
    if (threadIdx.x < NCAM)
        compute_cam_mat(b, threadIdx.x, l2i, iam, lam, smats + threadIdx.x * 16);
    bn_precompute(cb, gamma, beta, mean, var, s_scale, s_bias);
    __syncthreads();

    const int P = blockIdx.x * 64 + threadIdx.x;
    const int ix = P / NYV, iy = P % NYV;
    const float x = ix * 0.5f - 50.0f;
    const float y = iy * 0.5f - 50.0f;

    const __half* base = featW + (size_t)b * NCAM * HWF * COUT + cs * CHALF;
    const uint4* src[NZV];
    float vmask[NZV];
    #pragma unroll
    for (int iz = 0; iz < NZV; ++iz) {
        float z = iz * 1.5f - 4.7f;
        int off = project_point(smats, x, y, z);
        vmask[iz] = (off >= 0) ? 1.0f : 0.0f;
        src[iz] = reinterpret_cast<const uint4*>(
            base + (size_t)((off >= 0) ? off : 0) * COUT);
    }

    // Issue all 20 independent 16B gathers (4 z x 5 uint4 = 80B/lane/z).
    uint4 buf[NZV][5];
    #pragma unroll
    for (int iz = 0; iz < NZV; ++iz)
        #pragma unroll
        for (int i = 0; i < 5; i++) buf[iz][i] = src[iz][i];

    float acc[CHALF];
    #pragma unroll
    for (int k = 0; k < CHALF; k++) acc[k] = 0.f;
    #pragma unroll
    for (int iz = 0; iz < NZV; ++iz) {
        float m = vmask[iz];
        #pragma unroll
        for (int i = 0; i < 5; i++) {
            const __half2* h2 = reinterpret_cast<const __half2*>(&buf[iz][i]);
            #pragma unroll
            for (int k = 0; k < 4; k++) {
                float2 fv = __half22float2(h2[k]);
                acc[i * 8 + k * 2]     = fmaf(m, fv.x, acc[i * 8 + k * 2]);
                acc[i * 8 + k * 2 + 1] = fmaf(m, fv.y, acc[i * 8 + k * 2 + 1]);
            }
        }
    }

    float* op = out + ((size_t)b * COUT + cs * CHALF) * NPIX + P;
    #pragma unroll
    for (int k = 0; k < CHALF; k++) {
        int o = cs * CHALF + k;
        float val = fmaf(acc[k], s_scale[o], s_bias[o]);
        op[(size_t)k * NPIX] = fmaxf(val, 0.f);
    }
}

// ---------------------------------------------------------------------------
// Fallback (only if ws too small): fully fused fp32. Slow but correct.
// ---------------------------------------------------------------------------
__global__ __launch_bounds__(64) void k_bev_fb(const float* __restrict__ feat,
                                               const float* __restrict__ l2i,
                                               const float* __restrict__ iam,
                                               const float* __restrict__ lam,
                                               const float* __restrict__ W,
                                               const float* __restrict__ cb,
                                               const float* __restrict__ gamma,
                                               const float* __restrict__ beta,
                                               const float* __restrict__ mean,
                                               const float* __restrict__ var,
                                               float* __restrict__ out) {
    __shared__ float smats[NCAM * 16];
    __shared__ float s_scale[COUT];
    __shared__ float s_bias[COUT];
    const int b = blockIdx.y;
    if (threadIdx.x < NCAM)
        compute_cam_mat(b, threadIdx.x, l2i, iam, lam, smats + threadIdx.x * 16);
    bn_precompute(cb, gamma, beta, mean, var, s_scale, s_bias);
    __syncthreads();

    const int P = blockIdx.x * 64 + threadIdx.x;
    const int ix = P / NYV, iy = P % NYV;
    const float x = ix * 0.5f - 50.0f;
    const float y = iy * 0.5f - 50.0f;

    float acc[COUT];
    #pragma unroll
    for (int o = 0; o < COUT; o++) acc[o] = 0.f;

    for (int iz = 0; iz < NZV; ++iz) {
        float z = iz * 1.5f - 4.7f;
        int off = project_point(smats, x, y, z);
        if (off >= 0) {
            const float* fp = feat + (size_t)b * NCAM * CIN * HWF +
                              (size_t)(off / HWF) * CIN * HWF + (off % HWF);
            for (int c = 0; c < CIN; c++) {
                float fv = fp[(size_t)c * HWF];
                #pragma unroll 8
                for (int o = 0; o < COUT; o++) acc[o] = fmaf(fv, W[o * CIN + c], acc[o]);
            }
        }
    }

    float* op = out + (size_t)b * COUT * NPIX + P;
    for (int o = 0; o < COUT; o++) {
        float val = fmaf(acc[o], s_scale[o], s_bias[o]);
        op[(size_t)o * NPIX] = fmaxf(val, 0.f);
    }
}

extern "C" void kernel_launch(void* const* d_in, const int* in_sizes, int n_in,
                              void* d_out, int out_size, void* d_ws, size_t ws_size,
                              hipStream_t stream) {
    const float* feat  = (const float*)d_in[0];
    const float* l2i   = (const float*)d_in[1];
    const float* iam   = (const float*)d_in[2];
    const float* lam   = (const float*)d_in[3];
    const float* W     = (const float*)d_in[4];
    const float* cb    = (const float*)d_in[5];
    const float* gamma = (const float*)d_in[6];
    const float* beta  = (const float*)d_in[7];
    const float* mean  = (const float*)d_in[8];
    const float* var   = (const float*)d_in[9];
    float* out = (float*)d_out;

    if (ws_size >= WS_NEED) {
        __half* featWp = (__half*)d_ws;
        k_featw<<<dim3(22, 12, 4), 128, 0, stream>>>(feat, W, featWp);
        k_bev<<<dim3(625, 2, CSPLIT), 64, 0, stream>>>(featWp, l2i, iam, lam, cb,
                                                       gamma, beta, mean, var, out);
    } else {
        k_bev_fb<<<dim3(625, 2), 64, 0, stream>>>(feat, l2i, iam, lam, W, cb, gamma,
                                                  beta, mean, var, out);
    }
}

// Round 12
// 133.860 us; speedup vs baseline: 1.5293x; 1.0064x over previous
//
#include <hip/hip_runtime.h>
#include <hip/hip_fp16.h>

#define BATCH 2
#define NCAM 6
#define CIN 256
#define COUT 80
#define HFEAT 32
#define WFEAT 88
#define HWF (HFEAT * WFEAT)   // 2816
#define NXV 200
#define NYV 200
#define NZV 4
#define NPIX (NXV * NYV)      // 40000
#define BN_EPS 1e-5f
#define CSPLIT 2              // channel halves in k_bev
#define CHALF (COUT / CSPLIT) // 40

// ws layout: featW in fp16 (B*NCAM*HWF*COUT halfs = 5,406,720 B) at offset 0.
#define WS_NEED ((size_t)BATCH * NCAM * HWF * COUT * 2)

// ---------------------------------------------------------------------------
// Combined projection matrix per (b, cam) — folds lidar_aug^-1 and
// (iam_r @ l2i) into one 3x4 matrix + u/v post-offsets.
// ---------------------------------------------------------------------------
__device__ __forceinline__ void compute_cam_mat(int b, int cam,
                                                const float* __restrict__ l2i,
                                                const float* __restrict__ iam,
                                                const float* __restrict__ lam,
                                                float* __restrict__ O /*16*/) {
    const float* L = lam + b * 16;
    const float* A = iam + (b * NCAM + cam) * 16;
    const float* P = l2i + (b * NCAM + cam) * 16;
    float Tl[3][4];
    #pragma unroll
    for (int i = 0; i < 3; i++) {
        #pragma unroll
        for (int j = 0; j < 3; j++) Tl[i][j] = L[j * 4 + i];
        Tl[i][3] = -(L[0 * 4 + i] * L[0 * 4 + 3] +
                     L[1 * 4 + i] * L[1 * 4 + 3] +
                     L[2 * 4 + i] * L[2 * 4 + 3]);
    }
    float Pm[3][4];
    #pragma unroll
    for (int i = 0; i < 3; i++)
        #pragma unroll
        for (int j = 0; j < 4; j++) {
            float s = 0.f;
            #pragma unroll
            for (int k = 0; k < 3; k++) s += A[i * 4 + k] * P[k * 4 + j];
            Pm[i][j] = s;
        }
    #pragma unroll
    for (int i = 0; i < 3; i++) {
        #pragma unroll
        for (int j = 0; j < 4; j++) {
            float s = (j == 3) ? Pm[i][3] : 0.f;
            #pragma unroll
            for (int k = 0; k < 3; k++) s += Pm[i][k] * Tl[k][j];
            O[i * 4 + j] = s;
        }
    }
    O[12] = A[0 * 4 + 3];
    O[13] = A[1 * 4 + 3];
    O[14] = 0.f;
    O[15] = 0.f;
}

// ---------------------------------------------------------------------------
// featW[bc][hw][o] = (half) sum_c W[o][c] * feat[bc][c][hw]
// R10 counters: global-load-latency bound (FETCH 17.2MB -> half of feat
// from HBM ~900cy; VGPR=68 -> only ~2 c-iters in flight; VALUBusy 22%).
// Fix (re-run; R11 acquisition timed out) = LDS W-tile (consume side
// clean) + 16-deep feat register double-buffer (issue side deep): 16
// loads in flight while the other 16 feed 320 FMAs (~740cy) -- covers
// HBM latency. FMA order (c ascending, j inner) unchanged -> bitwise-
// identical. grid (22,12,4), block 128 (2 waves share the 20KB W tile).
// ---------------------------------------------------------------------------
__global__ __launch_bounds__(128) void k_featw(const float* __restrict__ feat,
                                               const float* __restrict__ W,
                                               __half* __restrict__ featW) {
    __shared__ __align__(16) float wl[CIN][20];   // [c][j], rows 80B (16B-mult)
    const int l = threadIdx.x;                     // 0..127
    const int bc = blockIdx.y;                     // 0..11
    const int og = blockIdx.z;                     // 0..3 (20 outputs each)

    // Stage W^T tile: 128 threads x 2 halves per j, global coalesced.
    #pragma unroll
    for (int j = 0; j < 20; j++) {
        wl[l][j]       = W[(og * 20 + j) * CIN + l];
        wl[l + 128][j] = W[(og * 20 + j) * CIN + l + 128];
    }
    __syncthreads();

    const int hw = blockIdx.x * 128 + l;           // 0..2815
    const float* f = feat + (size_t)bc * CIN * HWF + hw;

    float acc[20];
    #pragma unroll
    for (int j = 0; j < 20; j++) acc[j] = 0.f;

    float fbA[16], fbB[16];
    #pragma unroll
    for (int k = 0; k < 16; k++) fbA[k] = f[(size_t)k * HWF];

    #pragma unroll
    for (int cc = 0; cc < CIN; cc += 32) {
        // issue next 16 feat loads (c = cc+16 .. cc+31) into B
        #pragma unroll
        for (int k = 0; k < 16; k++) fbB[k] = f[(size_t)(cc + 16 + k) * HWF];
        // consume A (c = cc .. cc+15); W from LDS broadcast reads
        #pragma unroll
        for (int k = 0; k < 16; k++) {
            float v = fbA[k];
            const float4* wr = reinterpret_cast<const float4*>(&wl[cc + k][0]);
            float4 w0 = wr[0], w1 = wr[1], w2 = wr[2], w3 = wr[3], w4 = wr[4];
            acc[0]  = fmaf(v, w0.x, acc[0]);   acc[1]  = fmaf(v, w0.y, acc[1]);
            acc[2]  = fmaf(v, w0.z, acc[2]);   acc[3]  = fmaf(v, w0.w, acc[3]);
            acc[4]  = fmaf(v, w1.x, acc[4]);   acc[5]  = fmaf(v, w1.y, acc[5]);
            acc[6]  = fmaf(v, w1.z, acc[6]);   acc[7]  = fmaf(v, w1.w, acc[7]);
            acc[8]  = fmaf(v, w2.x, acc[8]);   acc[9]  = fmaf(v, w2.y, acc[9]);
            acc[10] = fmaf(v, w2.z, acc[10]);  acc[11] = fmaf(v, w2.w, acc[11]);
            acc[12] = fmaf(v, w3.x, acc[12]);  acc[13] = fmaf(v, w3.y, acc[13]);
            acc[14] = fmaf(v, w3.z, acc[14]);  acc[15] = fmaf(v, w3.w, acc[15]);
            acc[16] = fmaf(v, w4.x, acc[16]);  acc[17] = fmaf(v, w4.y, acc[17]);
            acc[18] = fmaf(v, w4.z, acc[18]);  acc[19] = fmaf(v, w4.w, acc[19]);
        }
        // issue next 16 feat loads (c = cc+32 .. cc+47) into A
        if (cc + 32 < CIN) {
            #pragma unroll
            for (int k = 0; k < 16; k++) fbA[k] = f[(size_t)(cc + 32 + k) * HWF];
        }
        // consume B (c = cc+16 .. cc+31)
        #pragma unroll
        for (int k = 0; k < 16; k++) {
            float v = fbB[k];
            const float4* wr = reinterpret_cast<const float4*>(&wl[cc + 16 + k][0]);
            float4 w0 = wr[0], w1 = wr[1], w2 = wr[2], w3 = wr[3], w4 = wr[4];
            acc[0]  = fmaf(v, w0.x, acc[0]);   acc[1]  = fmaf(v, w0.y, acc[1]);
            acc[2]  = fmaf(v, w0.z, acc[2]);   acc[3]  = fmaf(v, w0.w, acc[3]);
            acc[4]  = fmaf(v, w1.x, acc[4]);   acc[5]  = fmaf(v, w1.y, acc[5]);
            acc[6]  = fmaf(v, w1.z, acc[6]);   acc[7]  = fmaf(v, w1.w, acc[7]);
            acc[8]  = fmaf(v, w2.x, acc[8]);   acc[9]  = fmaf(v, w2.y, acc[9]);
            acc[10] = fmaf(v, w2.z, acc[10]);  acc[11] = fmaf(v, w2.w, acc[11]);
            acc[12] = fmaf(v, w3.x, acc[12]);  acc[13] = fmaf(v, w3.y, acc[13]);
            acc[14] = fmaf(v, w3.z, acc[14]);  acc[15] = fmaf(v, w3.w, acc[15]);
            acc[16] = fmaf(v, w4.x, acc[16]);  acc[17] = fmaf(v, w4.y, acc[17]);
            acc[18] = fmaf(v, w4.z, acc[18]);  acc[19] = fmaf(v, w4.w, acc[19]);
        }
    }

    // fp16 store: 10x half2 (4B) stores; dst byte offset is 4B-aligned.
    __half2* dst = reinterpret_cast<__half2*>(
        featW + ((size_t)bc * HWF + hw) * COUT + og * 20);
    #pragma unroll
    for (int j = 0; j < 10; j++)
        dst[j] = __floats2half2_rn(acc[2 * j], acc[2 * j + 1]);
}

// ---------------------------------------------------------------------------
// Projection of one voxel point -> (cam*HWF + v*WFEAT + u) or -1.
// rintf == jnp.round (half-even); strict Z>0; bounds in float space before
// the int cast; LAST valid camera wins (iterate 5..0).
// ---------------------------------------------------------------------------
__device__ __forceinline__ int project_point(const float* __restrict__ M /*6*16*/,
                                             float x, float y, float z) {
    for (int cam = NCAM - 1; cam >= 0; --cam) {
        const float* m = M + cam * 16;
        float Z = m[8] * x + m[9] * y + m[10] * z + m[11];
        if (Z > 0.f) {
            float u = (m[0] * x + m[1] * y + m[2] * z + m[3]) / Z + m[12];
            float v = (m[4] * x + m[5] * y + m[6] * z + m[7]) / Z + m[13];
            float uf = rintf(u * 0.125f);   // stride = 8, exact pow2 scale
            float vf = rintf(v * 0.125f);
            if (uf >= 0.f && uf < (float)WFEAT && vf >= 0.f && vf < (float)HFEAT) {
                return cam * HWF + (int)vf * WFEAT + (int)uf;
            }
        }
    }
    return -1;
}

// ---------------------------------------------------------------------------
// BN scale / folded-bias precompute into LDS (per block).
// ---------------------------------------------------------------------------
__device__ __forceinline__ void bn_precompute(const float* __restrict__ cb,
                                              const float* __restrict__ gamma,
                                              const float* __restrict__ beta,
                                              const float* __restrict__ mean,
                                              const float* __restrict__ var,
                                              float* __restrict__ s_scale,
                                              float* __restrict__ s_bias) {
    for (int o = threadIdx.x; o < COUT; o += 64) {
        float sc = gamma[o] / sqrtf(var[o] + BN_EPS);
        s_scale[o] = sc;
        s_bias[o] = (cb[o] - mean[o]) * sc + beta[o];
    }
}

// ---------------------------------------------------------------------------
// Main BEV kernel (unchanged; counters pending): 1 wave/block, lane = BEV
// pixel, block = 40 of 80 ch. Branch-free gathers, fp16 featW, fp32 accum.
// grid (625,2,2), block 64.
// ---------------------------------------------------------------------------
__global__ __launch_bounds__(64) void k_bev(const __half* __restrict__ featW,
                                            const float* __restrict__ l2i,
                                            const float* __restrict__ iam,
                                            const float* __restrict__ lam,
                                            const float* __restrict__ cb,
                                            const float* __restrict__ gamma,
                                            const float* __restrict__ beta,
                                            const float* __restrict__ mean,
                                            const float* __restrict__ var,
                                            float* __restrict__ out) {
    __shared__ float smats[NCAM * 16];
    __shared__ float s_scale[COUT];
    __shared__ float s_bias[COUT];
    const int b = blockIdx.y;
    const int cs = blockIdx.z;          // channel half: 0 or 1
    if (threadIdx.x < NCAM)
        compute_cam_mat(b, threadIdx.x, l2i, iam, lam, smats + threadIdx.x * 16);
    bn_precompute(cb, gamma, beta, mean, var, s_scale, s_bias);
    __syncthreads();

    const int P = blockIdx.x * 64 + threadIdx.x;
    const int ix = P / NYV, iy = P % NYV;
    const float x = ix * 0.5f - 50.0f;
    const float y = iy * 0.5f - 50.0f;

    const __half* base = featW + (size_t)b * NCAM * HWF * COUT + cs * CHALF;
    const uint4* src[NZV];
    float vmask[NZV];
    #pragma unroll
    for (int iz = 0; iz < NZV; ++iz) {
        float z = iz * 1.5f - 4.7f;
        int off = project_point(smats, x, y, z);
        vmask[iz] = (off >= 0) ? 1.0f : 0.0f;
        src[iz] = reinterpret_cast<const uint4*>(
            base + (size_t)((off >= 0) ? off : 0) * COUT);
    }

    // Issue all 20 independent 16B gathers (4 z x 5 uint4 = 80B/lane/z).
    uint4 buf[NZV][5];
    #pragma unroll
    for (int iz = 0; iz < NZV; ++iz)
        #pragma unroll
        for (int i = 0; i < 5; i++) buf[iz][i] = src[iz][i];

    float acc[CHALF];
    #pragma unroll
    for (int k = 0; k < CHALF; k++) acc[k] = 0.f;
    #pragma unroll
    for (int iz = 0; iz < NZV; ++iz) {
        float m = vmask[iz];
        #pragma unroll
        for (int i = 0; i < 5; i++) {
            const __half2* h2 = reinterpret_cast<const __half2*>(&buf[iz][i]);
            #pragma unroll
            for (int k = 0; k < 4; k++) {
                float2 fv = __half22float2(h2[k]);
                acc[i * 8 + k * 2]     = fmaf(m, fv.x, acc[i * 8 + k * 2]);
                acc[i * 8 + k * 2 + 1] = fmaf(m, fv.y, acc[i * 8 + k * 2 + 1]);
            }
        }
    }

    float* op = out + ((size_t)b * COUT + cs * CHALF) * NPIX + P;
    #pragma unroll
    for (int k = 0; k < CHALF; k++) {
        int o = cs * CHALF + k;
        float val = fmaf(acc[k], s_scale[o], s_bias[o]);
        op[(size_t)k * NPIX] = fmaxf(val, 0.f);
    }
}

// ---------------------------------------------------------------------------
// Fallback (only if ws too small): fully fused fp32. Slow but correct.
// ---------------------------------------------------------------------------
__global__ __launch_bounds__(64) void k_bev_fb(const float* __restrict__ feat,
                                               const float* __restrict__ l2i,
                                               const float* __restrict__ iam,
                                               const float* __restrict__ lam,
                                               const float* __restrict__ W,
                                               const float* __restrict__ cb,
                                               const float* __restrict__ gamma,
                                               const float* __restrict__ beta,
                                               const float* __restrict__ mean,
                                               const float* __restrict__ var,
                                               float* __restrict__ out) {
    __shared__ float smats[NCAM * 16];
    __shared__ float s_scale[COUT];
    __shared__ float s_bias[COUT];
    const int b = blockIdx.y;
    if (threadIdx.x < NCAM)
        compute_cam_mat(b, threadIdx.x, l2i, iam, lam, smats + threadIdx.x * 16);
    bn_precompute(cb, gamma, beta, mean, var, s_scale, s_bias);
    __syncthreads();

    const int P = blockIdx.x * 64 + threadIdx.x;
    const int ix = P / NYV, iy = P % NYV;
    const float x = ix * 0.5f - 50.0f;
    const float y = iy * 0.5f - 50.0f;

    float acc[COUT];
    #pragma unroll
    for (int o = 0; o < COUT; o++) acc[o] = 0.f;

    for (int iz = 0; iz < NZV; ++iz) {
        float z = iz * 1.5f - 4.7f;
        int off = project_point(smats, x, y, z);
        if (off >= 0) {
            const float* fp = feat + (size_t)b * NCAM * CIN * HWF +
                              (size_t)(off / HWF) * CIN * HWF + (off % HWF);
            for (int c = 0; c < CIN; c++) {
                float fv = fp[(size_t)c * HWF];
                #pragma unroll 8
                for (int o = 0; o < COUT; o++) acc[o] = fmaf(fv, W[o * CIN + c], acc[o]);
            }
        }
    }

    float* op = out + (size_t)b * COUT * NPIX + P;
    for (int o = 0; o < COUT; o++) {
        float val = fmaf(acc[o], s_scale[o], s_bias[o]);
        op[(size_t)o * NPIX] = fmaxf(val, 0.f);
    }
}

extern "C" void kernel_launch(void* const* d_in, const int* in_sizes, int n_in,
                              void* d_out, int out_size, void* d_ws, size_t ws_size,
                              hipStream_t stream) {
    const float* feat  = (const float*)d_in[0];
    const float* l2i   = (const float*)d_in[1];
    const float* iam   = (const float*)d_in[2];
    const float* lam   = (const float*)d_in[3];
    const float* W     = (const float*)d_in[4];
    const float* cb    = (const float*)d_in[5];
    const float* gamma = (const float*)d_in[6];
    const float* beta  = (const float*)d_in[7];
    const float* mean  = (const float*)d_in[8];
    const float* var   = (const float*)d_in[9];
    float* out = (float*)d_out;

    if (ws_size >= WS_NEED) {
        __half* featWp = (__half*)d_ws;
        k_featw<<<dim3(22, 12, 4), 128, 0, stream>>>(feat, W, featWp);
        k_bev<<<dim3(625, 2, CSPLIT), 64, 0, stream>>>(featWp, l2i, iam, lam, cb,
                                                       gamma, beta, mean, var, out);
    } else {
        k_bev_fb<<<dim3(625, 2), 64, 0, stream>>>(feat, l2i, iam, lam, W, cb, gamma,
                                                  beta, mean, var, out);
    }
}